// Round 11
// baseline (305.942 us; speedup 1.0000x reference)
//
#include <hip/hip_runtime.h>

#define N 8192
#define D 256

typedef short short8 __attribute__((ext_vector_type(8)));
typedef float f32x4 __attribute__((ext_vector_type(4)));

__device__ __forceinline__ unsigned short f2bf(float f) {
    unsigned int u = __float_as_uint(f);
    u += 0x7fffu + ((u >> 16) & 1u);   // RNE
    return (unsigned short)(u >> 16);
}
__device__ __forceinline__ float bf2f(unsigned short h) {
    return __uint_as_float(((unsigned int)h) << 16);
}

// async global->LDS, 16B per lane; dst is wave-uniform base, lane i lands at dst + i*16
#define GLDS16(g, l) __builtin_amdgcn_global_load_lds(                      \
    (const __attribute__((address_space(1))) void*)(g),                     \
    (__attribute__((address_space(3))) void*)(l), 16, 0, 0)

// Kernel 0: fp32 -> bf16 pre-conversion + row squared norms (of bf16-rounded
// values, consistent with the MFMA Gram) + zero the S/L accumulators.
__global__ __launch_bounds__(256) void k_cvt(const float* __restrict__ x,
                                             unsigned short* __restrict__ xb,
                                             float* __restrict__ sq,
                                             float* __restrict__ Sarr,
                                             float* __restrict__ Larr) {
    const int wv = threadIdx.x >> 6, lane = threadIdx.x & 63;
    const int row = blockIdx.x * 4 + wv;
    const float4 v = ((const float4*)x)[(size_t)row * 64 + lane];
    unsigned short pa = f2bf(v.x), pb = f2bf(v.y), pc = f2bf(v.z), pd = f2bf(v.w);
    float a = bf2f(pa), b = bf2f(pb), c = bf2f(pc), d = bf2f(pd);
    float s = a * a + b * b + c * c + d * d;
    ((ushort4*)xb)[(size_t)row * 64 + lane] = make_ushort4(pa, pb, pc, pd);
#pragma unroll
    for (int m = 1; m < 64; m <<= 1) s += __shfl_xor(s, m, 64);
    if (lane == 0) {
        sq[row] = s;
        Sarr[row] = 0.0f;
        Larr[row] = 0.0f;
    }
}

// Kernel 1: R10 kernel at 4 BLOCKS/CU. 64 rows/wave (256-row blocks),
// fragment-sequential zero-conflict LDS, screened exp2 epilogue — unchanged.
// Occupancy lever: 32-col tiles (2 x 16 KB ping-pong = 32 KB LDS), grid
// (32,32) = 1024 blocks, __launch_bounds__(256,4) -> 4 waves/SIMD so the
// per-wave serial ds_read->MFMA->screen stream overlaps across waves
// (R6-R10 showed the pipes were SUMMING at 2 waves/SIMD, not overlapping).
// Fragment-sequential layout: segment s = tc*8+kk holds at lane*16 exactly
// lane (c,q8)'s short8 for MFMA fragment (tc,kk); staging source carries
// the gather; LDS write and read are both canonical lane*16 -> 0 conflicts.
__global__ __launch_bounds__(256, 4) void k_gram(const unsigned short* __restrict__ xb,
                                                 const float* __restrict__ sq,
                                                 const float* __restrict__ temp,
                                                 float* __restrict__ Sarr,
                                                 float* __restrict__ Larr) {
    __shared__ unsigned short Bs[2][32 * D];   // 2 x 16 KB, fragment-sequential

    const int tid = threadIdx.x;
    const int wv = tid >> 6, lane = tid & 63;
    const int q8 = lane >> 4, c = lane & 15;
    const int rowbase = blockIdx.x * 256;
    const int ybase = blockIdx.y * 256;
    const float T = temp[0];
    const float LOG2E = 1.44269504f;
    const float s2 = -LOG2E / (2.0f * T * T);   // log2-scaled; t2 = c2*g + ar + bc
    const float c2 = -2.0f * s2;

    // A fragments in registers: wave wv owns rows rowbase + wv*64 .. +63
    short8 av[4][8];
#pragma unroll
    for (int tr = 0; tr < 4; ++tr) {
        const unsigned short* ap = xb + (size_t)(rowbase + wv * 64 + tr * 16 + c) * D;
#pragma unroll
        for (int kk = 0; kk < 8; ++kk)
            av[tr][kk] = *(const short8*)(ap + kk * 32 + q8 * 8);
    }
    float ar[16];   // sq[row] * s2 (negative)
#pragma unroll
    for (int tr = 0; tr < 4; ++tr)
#pragma unroll
        for (int r = 0; r < 4; ++r)
            ar[tr * 4 + r] = sq[rowbase + wv * 64 + tr * 16 + q8 * 4 + r] * s2;
    float armax = ar[0];
#pragma unroll
    for (int k = 1; k < 16; ++k) armax = fmaxf(armax, ar[k]);

    float Sr[16], Mr[16];
#pragma unroll
    for (int k = 0; k < 16; ++k) { Sr[k] = 0.f; Mr[k] = 0.f; }

    // staging: 16 segs of 1 KB per 32-col tile; wave wv stages segs wv*4..+3
    // src(seg) = xb[(tb + (seg>>3)*16 + c)*D + (seg&7)*32 + q8*8]  (16B/lane)
#pragma unroll
    for (int g2 = 0; g2 < 4; ++g2) {
        int s = wv * 4 + g2;
        const unsigned short* src =
            xb + (size_t)(ybase + ((s >> 3) << 4) + c) * D + ((s & 7) << 5) + (q8 << 3);
        GLDS16(src, &Bs[0][0] + s * 512);
    }

    for (int ht = 0; ht < 8; ++ht) {
        const int tilebase = ybase + ht * 32;
        const int cur = ht & 1;

        __syncthreads();   // drains stage of ht; fences buffer reuse (ht-2)

        if (ht < 7) {
            const int nb = tilebase + 32;
#pragma unroll
            for (int g2 = 0; g2 < 4; ++g2) {
                int s = wv * 4 + g2;
                const unsigned short* src =
                    xb + (size_t)(nb + ((s >> 3) << 4) + c) * D + ((s & 7) << 5) + (q8 << 3);
                GLDS16(src, &Bs[cur ^ 1][0] + s * 512);
            }
        }

#pragma unroll
        for (int tc = 0; tc < 2; ++tc) {
            const float bc = sq[tilebase + tc * 16 + c] * s2;
            // fragment-sequential: lane's data for (tc,kk) at seg*1024B + lane*16B
            const unsigned short* bb = &Bs[cur][0] + tc * 8 * 512 + lane * 8;

            short8 bva[4];
#pragma unroll
            for (int kk = 0; kk < 4; ++kk)
                bva[kk] = *(const short8*)(bb + kk * 512);

            f32x4 acc[4];
#pragma unroll
            for (int tr = 0; tr < 4; ++tr)
#pragma unroll
                for (int r = 0; r < 4; ++r) acc[tr][r] = 0.0f;

#pragma unroll
            for (int kk = 0; kk < 4; ++kk)
#pragma unroll
                for (int tr = 0; tr < 4; ++tr)
                    acc[tr] = __builtin_amdgcn_mfma_f32_16x16x32_bf16(
                        av[tr][kk], bva[kk], acc[tr], 0, 0, 0);

            short8 bvb[4];
#pragma unroll
            for (int kk = 0; kk < 4; ++kk)
                bvb[kk] = *(const short8*)(bb + (kk + 4) * 512);

#pragma unroll
            for (int kk = 0; kk < 4; ++kk)
#pragma unroll
                for (int tr = 0; tr < 4; ++tr)
                    acc[tr] = __builtin_amdgcn_mfma_f32_16x16x32_bf16(
                        av[tr][kk + 4], bvb[kk], acc[tr], 0, 0, 0);

            // screen: conservative upper bound on t2 over this lane's 16 elems
            float gmax = acc[0][0];
#pragma unroll
            for (int tr = 0; tr < 4; ++tr)
#pragma unroll
                for (int r = 0; r < 4; ++r) gmax = fmaxf(gmax, acc[tr][r]);
            const float bound = fmaf(gmax, c2, armax + bc);

            if (__any(bound >= -115.0f)) {
                // exact slow path (diagonal-touching tiles, ~1%)
#pragma unroll
                for (int tr = 0; tr < 4; ++tr)
#pragma unroll
                    for (int r = 0; r < 4; ++r) {
                        float g = acc[tr][r];
                        float t2 = fminf(fmaf(g, c2, ar[tr * 4 + r] + bc), 0.0f);
                        float e = __builtin_amdgcn_exp2f(t2);
                        Sr[tr * 4 + r] += e;
                        Mr[tr * 4 + r] = fmaf(e, t2, Mr[tr * 4 + r]);
                    }
            }
            // else: all values underflow fp32 -> contribute exactly 0
        }
    }

    // row-sum commit: reduce across the 16 col-lanes (lane bits 0..3)
#pragma unroll
    for (int m = 1; m <= 8; m <<= 1)
#pragma unroll
        for (int k = 0; k < 16; ++k) {
            Sr[k] += __shfl_xor(Sr[k], m, 64);
            Mr[k] += __shfl_xor(Mr[k], m, 64);
        }
    if (c == 0) {
        const float LN2 = 0.69314718f;   // Mr holds sum e*log2(k); rescale to ln
#pragma unroll
        for (int k = 0; k < 16; ++k) {
            int row = rowbase + wv * 64 + (k >> 2) * 16 + q8 * 4 + (k & 3);
            atomicAdd(&Sarr[row], Sr[k]);
            atomicAdd(&Larr[row], Mr[k] * LN2);
        }
    }
}

// Kernel 2 (merged ctrl+scale): per row H = log(S) - L/S,
// cs = sigmoid(-(H - target)/T); write scaled features + control signal.
__global__ __launch_bounds__(256) void k_finish(const float* __restrict__ x,
                                                const float* __restrict__ Sarr,
                                                const float* __restrict__ Larr,
                                                const float* __restrict__ target,
                                                const float* __restrict__ temp,
                                                float* __restrict__ out) {
    const int gid = blockIdx.x * 256 + threadIdx.x;  // float4 index
    const int row = gid >> 6;                        // 64 float4 per row
    float S = Sarr[row], L = Larr[row];
    float H = __logf(S) - L / S;
    float z = (H - target[0]) / temp[0];
    float cs = 1.0f / (1.0f + __expf(z));
    float4 v = ((const float4*)x)[gid];
    float4 o;
    o.x = v.x * cs; o.y = v.y * cs; o.z = v.z * cs; o.w = v.w * cs;
    ((float4*)out)[gid] = o;
    if ((gid & 63) == 0) out[(size_t)N * D + row] = cs;  // control_signal section
}

extern "C" void kernel_launch(void* const* d_in, const int* in_sizes, int n_in,
                              void* d_out, int out_size, void* d_ws, size_t ws_size,
                              hipStream_t stream) {
    const float* x = (const float*)d_in[0];       // features [4,2048,256]
    const float* target = (const float*)d_in[7];  // target_entropy [1]
    const float* temp = (const float*)d_in[8];    // temperature [1]
    float* out = (float*)d_out;

    float* wsf = (float*)d_ws;
    float* sq = wsf;
    float* Sarr = wsf + N;
    float* Larr = wsf + 2 * N;

    // bf16 copy of X: in ws if it fits, else park it in d_out's first 4 MB
    // (k_finish only writes d_out after k_gram has fully consumed xb)
    const size_t need = 3 * (size_t)N * sizeof(float) + (size_t)N * D * sizeof(unsigned short);
    unsigned short* xb = (ws_size >= need) ? (unsigned short*)(wsf + 3 * N)
                                           : (unsigned short*)d_out;

    k_cvt<<<N / 4, 256, 0, stream>>>(x, xb, sq, Sarr, Larr);
    k_gram<<<dim3(32, 32), 256, 0, stream>>>(xb, sq, temp, Sarr, Larr);
    k_finish<<<(N * (D / 4)) / 256, 256, 0, stream>>>(x, Sarr, Larr, target, temp, out);
}

// Round 12
// 124.744 us; speedup vs baseline: 2.4526x; 2.4526x over previous
//
#include <hip/hip_runtime.h>

#define N 8192
#define D 256

typedef short short8 __attribute__((ext_vector_type(8)));
typedef float f32x4 __attribute__((ext_vector_type(4)));

__device__ __forceinline__ unsigned short f2bf(float f) {
    unsigned int u = __float_as_uint(f);
    u += 0x7fffu + ((u >> 16) & 1u);   // RNE
    return (unsigned short)(u >> 16);
}
__device__ __forceinline__ float bf2f(unsigned short h) {
    return __uint_as_float(((unsigned int)h) << 16);
}

// async global->LDS, 16B per lane; dst is wave-uniform base, lane i lands at dst + i*16
#define GLDS16(g, l) __builtin_amdgcn_global_load_lds(                      \
    (const __attribute__((address_space(1))) void*)(g),                     \
    (__attribute__((address_space(3))) void*)(l), 16, 0, 0)

// Kernel 0: fp32 -> bf16 pre-conversion + row squared norms (of bf16-rounded
// values, consistent with the MFMA Gram) + zero the S/L accumulators.
__global__ __launch_bounds__(256) void k_cvt(const float* __restrict__ x,
                                             unsigned short* __restrict__ xb,
                                             float* __restrict__ sq,
                                             float* __restrict__ Sarr,
                                             float* __restrict__ Larr) {
    const int wv = threadIdx.x >> 6, lane = threadIdx.x & 63;
    const int row = blockIdx.x * 4 + wv;
    const float4 v = ((const float4*)x)[(size_t)row * 64 + lane];
    unsigned short pa = f2bf(v.x), pb = f2bf(v.y), pc = f2bf(v.z), pd = f2bf(v.w);
    float a = bf2f(pa), b = bf2f(pb), c = bf2f(pc), d = bf2f(pd);
    float s = a * a + b * b + c * c + d * d;
    ((ushort4*)xb)[(size_t)row * 64 + lane] = make_ushort4(pa, pb, pc, pd);
#pragma unroll
    for (int m = 1; m < 64; m <<= 1) s += __shfl_xor(s, m, 64);
    if (lane == 0) {
        sq[row] = s;
        Sarr[row] = 0.0f;
        Larr[row] = 0.0f;
    }
}

// Kernel 1: 32 ROWS/WAVE (128-row blocks, av = 64 VGPRs -> fits the 128-VGPR
// budget of __launch_bounds__(256,4), unlike R11's 64-rows/wave) x
// fragment-sequential zero-conflict LDS (R10) x 4 BLOCKS/CU.
// Grid (64,16) = 1024 blocks = 4/CU, 16 waves/CU: the per-wave serial
// ds_read -> MFMA -> screen stream now overlaps ACROSS waves (R6-R10 showed
// pipes summing at 2 waves/SIMD). 2 x 16 KB ping-pong, 32-col tiles.
// Fragment-sequential: segment s = tc*8+kk holds at lane*16 exactly lane
// (c,q8)'s short8 for MFMA fragment (tc,kk); staging source carries the
// gather; LDS write and read both canonical lane*16 -> 0 bank conflicts.
// Screened exp2 epilogue: skip tiles where every kernel value underflows
// fp32 (identical to the reference's own arithmetic -> absmax 0).
__global__ __launch_bounds__(256, 4) void k_gram(const unsigned short* __restrict__ xb,
                                                 const float* __restrict__ sq,
                                                 const float* __restrict__ temp,
                                                 float* __restrict__ Sarr,
                                                 float* __restrict__ Larr) {
    __shared__ unsigned short Bs[2][32 * D];   // 2 x 16 KB, fragment-sequential

    const int tid = threadIdx.x;
    const int wv = tid >> 6, lane = tid & 63;
    const int q8 = lane >> 4, c = lane & 15;
    const int rowbase = blockIdx.x * 128;
    const int ybase = blockIdx.y * 512;
    const float T = temp[0];
    const float LOG2E = 1.44269504f;
    const float s2 = -LOG2E / (2.0f * T * T);   // log2-scaled; t2 = c2*g + ar + bc
    const float c2 = -2.0f * s2;

    // A fragments in registers: wave wv owns rows rowbase + wv*32 .. +31
    short8 av[2][8];
#pragma unroll
    for (int tr = 0; tr < 2; ++tr) {
        const unsigned short* ap = xb + (size_t)(rowbase + wv * 32 + tr * 16 + c) * D;
#pragma unroll
        for (int kk = 0; kk < 8; ++kk)
            av[tr][kk] = *(const short8*)(ap + kk * 32 + q8 * 8);
    }
    float ar[8];   // sq[row] * s2 (negative)
#pragma unroll
    for (int tr = 0; tr < 2; ++tr)
#pragma unroll
        for (int r = 0; r < 4; ++r)
            ar[tr * 4 + r] = sq[rowbase + wv * 32 + tr * 16 + q8 * 4 + r] * s2;
    float armax = ar[0];
#pragma unroll
    for (int k = 1; k < 8; ++k) armax = fmaxf(armax, ar[k]);

    float Sr[8], Mr[8];
#pragma unroll
    for (int k = 0; k < 8; ++k) { Sr[k] = 0.f; Mr[k] = 0.f; }

    // staging: 32-col tile = 16 segs of 1 KB; wave wv stages segs wv*4..+3
    // seg s: tc = s>>3, kk = s&7; lane fetches the 16 B for (c,q8) of (tc,kk)
#pragma unroll
    for (int g2 = 0; g2 < 4; ++g2) {
        int s = wv * 4 + g2;
        const unsigned short* src =
            xb + (size_t)(ybase + ((s >> 3) << 4) + c) * D + ((s & 7) << 5) + (q8 << 3);
        GLDS16(src, &Bs[0][0] + s * 512);
    }

    for (int ht = 0; ht < 16; ++ht) {
        const int tilebase = ybase + ht * 32;
        const int cur = ht & 1;

        __syncthreads();   // drains stage of ht; fences buffer reuse (ht-2)

        if (ht < 15) {
            const int nb = tilebase + 32;
#pragma unroll
            for (int g2 = 0; g2 < 4; ++g2) {
                int s = wv * 4 + g2;
                const unsigned short* src =
                    xb + (size_t)(nb + ((s >> 3) << 4) + c) * D + ((s & 7) << 5) + (q8 << 3);
                GLDS16(src, &Bs[cur ^ 1][0] + s * 512);
            }
        }

#pragma unroll
        for (int tc = 0; tc < 2; ++tc) {
            const float bc = sq[tilebase + tc * 16 + c] * s2;
            // fragment-sequential: lane's data for (tc,kk) at seg*1024B + lane*16B
            const unsigned short* bb = &Bs[cur][0] + tc * 8 * 512 + lane * 8;

            short8 bva[4];
#pragma unroll
            for (int kk = 0; kk < 4; ++kk)
                bva[kk] = *(const short8*)(bb + kk * 512);

            f32x4 acc[2];
#pragma unroll
            for (int tr = 0; tr < 2; ++tr)
#pragma unroll
                for (int r = 0; r < 4; ++r) acc[tr][r] = 0.0f;

#pragma unroll
            for (int kk = 0; kk < 4; ++kk)
#pragma unroll
                for (int tr = 0; tr < 2; ++tr)
                    acc[tr] = __builtin_amdgcn_mfma_f32_16x16x32_bf16(
                        av[tr][kk], bva[kk], acc[tr], 0, 0, 0);

            short8 bvb[4];
#pragma unroll
            for (int kk = 0; kk < 4; ++kk)
                bvb[kk] = *(const short8*)(bb + (kk + 4) * 512);

#pragma unroll
            for (int kk = 0; kk < 4; ++kk)
#pragma unroll
                for (int tr = 0; tr < 2; ++tr)
                    acc[tr] = __builtin_amdgcn_mfma_f32_16x16x32_bf16(
                        av[tr][kk + 4], bvb[kk], acc[tr], 0, 0, 0);

            // screen: conservative upper bound on t2 over this lane's 8 elems
            float gmax = fmaxf(
                fmaxf(fmaxf(acc[0][0], acc[0][1]), fmaxf(acc[0][2], acc[0][3])),
                fmaxf(fmaxf(acc[1][0], acc[1][1]), fmaxf(acc[1][2], acc[1][3])));
            const float bound = fmaf(gmax, c2, armax + bc);

            if (__any(bound >= -115.0f)) {
                // exact slow path (diagonal-touching tiles, ~1%)
#pragma unroll
                for (int tr = 0; tr < 2; ++tr)
#pragma unroll
                    for (int r = 0; r < 4; ++r) {
                        float g = acc[tr][r];
                        float t2 = fminf(fmaf(g, c2, ar[tr * 4 + r] + bc), 0.0f);
                        float e = __builtin_amdgcn_exp2f(t2);
                        Sr[tr * 4 + r] += e;
                        Mr[tr * 4 + r] = fmaf(e, t2, Mr[tr * 4 + r]);
                    }
            }
            // else: all values underflow fp32 -> contribute exactly 0
        }
    }

    // row-sum commit: reduce across the 16 col-lanes (lane bits 0..3)
#pragma unroll
    for (int m = 1; m <= 8; m <<= 1)
#pragma unroll
        for (int k = 0; k < 8; ++k) {
            Sr[k] += __shfl_xor(Sr[k], m, 64);
            Mr[k] += __shfl_xor(Mr[k], m, 64);
        }
    if (c == 0) {
        const float LN2 = 0.69314718f;   // Mr holds sum e*log2(k); rescale to ln
#pragma unroll
        for (int k = 0; k < 8; ++k) {
            int row = rowbase + wv * 32 + (k >> 2) * 16 + q8 * 4 + (k & 3);
            atomicAdd(&Sarr[row], Sr[k]);
            atomicAdd(&Larr[row], Mr[k] * LN2);
        }
    }
}

// Kernel 2 (merged ctrl+scale): per row H = log(S) - L/S,
// cs = sigmoid(-(H - target)/T); write scaled features + control signal.
__global__ __launch_bounds__(256) void k_finish(const float* __restrict__ x,
                                                const float* __restrict__ Sarr,
                                                const float* __restrict__ Larr,
                                                const float* __restrict__ target,
                                                const float* __restrict__ temp,
                                                float* __restrict__ out) {
    const int gid = blockIdx.x * 256 + threadIdx.x;  // float4 index
    const int row = gid >> 6;                        // 64 float4 per row
    float S = Sarr[row], L = Larr[row];
    float H = __logf(S) - L / S;
    float z = (H - target[0]) / temp[0];
    float cs = 1.0f / (1.0f + __expf(z));
    float4 v = ((const float4*)x)[gid];
    float4 o;
    o.x = v.x * cs; o.y = v.y * cs; o.z = v.z * cs; o.w = v.w * cs;
    ((float4*)out)[gid] = o;
    if ((gid & 63) == 0) out[(size_t)N * D + row] = cs;  // control_signal section
}

extern "C" void kernel_launch(void* const* d_in, const int* in_sizes, int n_in,
                              void* d_out, int out_size, void* d_ws, size_t ws_size,
                              hipStream_t stream) {
    const float* x = (const float*)d_in[0];       // features [4,2048,256]
    const float* target = (const float*)d_in[7];  // target_entropy [1]
    const float* temp = (const float*)d_in[8];    // temperature [1]
    float* out = (float*)d_out;

    float* wsf = (float*)d_ws;
    float* sq = wsf;
    float* Sarr = wsf + N;
    float* Larr = wsf + 2 * N;

    // bf16 copy of X: in ws if it fits, else park it in d_out's first 4 MB
    // (k_finish only writes d_out after k_gram has fully consumed xb)
    const size_t need = 3 * (size_t)N * sizeof(float) + (size_t)N * D * sizeof(unsigned short);
    unsigned short* xb = (ws_size >= need) ? (unsigned short*)(wsf + 3 * N)
                                           : (unsigned short*)d_out;

    k_cvt<<<N / 4, 256, 0, stream>>>(x, xb, sq, Sarr, Larr);
    k_gram<<<dim3(64, 16), 256, 0, stream>>>(xb, sq, temp, Sarr, Larr);
    k_finish<<<(N * (D / 4)) / 256, 256, 0, stream>>>(x, Sarr, Larr, target, temp, out);
}

// Round 13
// 113.267 us; speedup vs baseline: 2.7011x; 1.1013x over previous
//
#include <hip/hip_runtime.h>

#define N 8192
#define D 256

typedef short short8 __attribute__((ext_vector_type(8)));
typedef float f32x4 __attribute__((ext_vector_type(4)));

__device__ __forceinline__ unsigned short f2bf(float f) {
    unsigned int u = __float_as_uint(f);
    u += 0x7fffu + ((u >> 16) & 1u);   // RNE
    return (unsigned short)(u >> 16);
}
__device__ __forceinline__ float bf2f(unsigned short h) {
    return __uint_as_float(((unsigned int)h) << 16);
}

// async global->LDS, 16B per lane; dst is wave-uniform base + lane*16;
// src is a normal per-lane VGPR address.
#define GLDS16(g, l) __builtin_amdgcn_global_load_lds(                      \
    (const __attribute__((address_space(1))) void*)(g),                     \
    (__attribute__((address_space(3))) void*)(l), 16, 0, 0)

// Kernel 0: fp32 -> bf16 conversion into FRAGMENT-MAJOR layout xb2:
// 16B chunk index ((row>>4)*8 + kk)*64 + lane  holds
// X[(row>>4)*16 + (lane&15)][kk*32 + (lane>>4)*8 .. +8)  as bf16.
// A 16-row group x K=256 = 8 KB is contiguous; any 64-col MFMA tile is a
// contiguous 32 KB block -> coalesced GLDS16 staging AND zero-conflict
// fragment-sequential LDS. Also: row squared norms (of the bf16-rounded
// values) + zero the S/L accumulators.
__global__ __launch_bounds__(256) void k_cvt(const float* __restrict__ x,
                                             unsigned short* __restrict__ xb2,
                                             float* __restrict__ sq,
                                             float* __restrict__ Sarr,
                                             float* __restrict__ Larr) {
    const int wv = threadIdx.x >> 6, lane = threadIdx.x & 63;
    const int c = lane & 15, q8 = lane >> 4;
    const int grp = blockIdx.x * 4 + wv;      // 16-row group
    const int row = grp * 16 + c;

    float ssum = 0.0f;
#pragma unroll
    for (int kk = 0; kk < 8; ++kk) {
        const float4* gp = (const float4*)(x + (size_t)row * D + kk * 32 + q8 * 8);
        float4 v0 = gp[0], v1 = gp[1];
        unsigned short h[8];
        h[0] = f2bf(v0.x); h[1] = f2bf(v0.y); h[2] = f2bf(v0.z); h[3] = f2bf(v0.w);
        h[4] = f2bf(v1.x); h[5] = f2bf(v1.y); h[6] = f2bf(v1.z); h[7] = f2bf(v1.w);
        short8 p;
#pragma unroll
        for (int i = 0; i < 8; ++i) {
            float f = bf2f(h[i]);
            ssum = fmaf(f, f, ssum);
            p[i] = (short)h[i];
        }
        ((short8*)xb2)[(grp * 8 + kk) * 64 + lane] = p;   // lane-contiguous store
    }
    // reduce over the 4 q8 lanes sharing this row (lane bits 4..5)
    ssum += __shfl_xor(ssum, 16, 64);
    ssum += __shfl_xor(ssum, 32, 64);
    if (q8 == 0) {
        sq[row] = ssum;
        Sarr[row] = 0.0f;
        Larr[row] = 0.0f;
    }
}

// Kernel 1: R10 body (64 rows/wave, 256-row blocks, 2 x 32 KB ping-pong,
// fragment-sequential zero-conflict LDS, screened exp2 epilogue) with all
// loads from the fragment-major xb2:
//  - A fragments: coalesced lane-contiguous reads;
//  - B staging: each 64-col tile is a CONTIGUOUS 32 KB block of xb2 ->
//    GLDS16 reads contiguous 1 KB per segment (no 64B-sector gather ->
//    removes R10/R12's ~10 us L2-side staging penalty).
// Additive-pipe model: LDS-read 10.2 + MFMA 16.5 + VALU ~7 + stage ~2.5
// => predicted ~37 us.
__global__ __launch_bounds__(256, 2) void k_gram(const unsigned short* __restrict__ xb2,
                                                 const float* __restrict__ sq,
                                                 const float* __restrict__ temp,
                                                 float* __restrict__ Sarr,
                                                 float* __restrict__ Larr) {
    __shared__ unsigned short Bs[2][64 * D];   // 2 x 32 KB, fragment-sequential

    const int tid = threadIdx.x;
    const int wv = tid >> 6, lane = tid & 63;
    const int q8 = lane >> 4, c = lane & 15;
    const int rowbase = blockIdx.x * 256;
    const int ybase = blockIdx.y * 512;
    const float T = temp[0];
    const float LOG2E = 1.44269504f;
    const float s2 = -LOG2E / (2.0f * T * T);   // log2-scaled; t2 = c2*g + ar + bc
    const float c2 = -2.0f * s2;

    // A fragments: wave wv owns rows rowbase + wv*64 .. +63 (groups +wv*4+tr)
    short8 av[4][8];
#pragma unroll
    for (int tr = 0; tr < 4; ++tr) {
        const int grp = (rowbase >> 4) + wv * 4 + tr;
#pragma unroll
        for (int kk = 0; kk < 8; ++kk)
            av[tr][kk] = ((const short8*)xb2)[(grp * 8 + kk) * 64 + lane];
    }
    float ar[16];   // sq[row] * s2 (negative)
#pragma unroll
    for (int tr = 0; tr < 4; ++tr)
#pragma unroll
        for (int r = 0; r < 4; ++r)
            ar[tr * 4 + r] = sq[rowbase + wv * 64 + tr * 16 + q8 * 4 + r] * s2;
    float armax = ar[0];
#pragma unroll
    for (int k = 1; k < 16; ++k) armax = fmaxf(armax, ar[k]);

    float Sr[16], Mr[16];
#pragma unroll
    for (int k = 0; k < 16; ++k) { Sr[k] = 0.f; Mr[k] = 0.f; }

    // staging: 64-col tile = contiguous 32 KB of xb2 = 32 segs of 1 KB;
    // wave wv stages segs wv*8 .. +7; per-lane src = tilechunk + s*512 + lane*8
#pragma unroll
    for (int g2 = 0; g2 < 8; ++g2) {
        int s = wv * 8 + g2;
        const unsigned short* src = xb2 + (size_t)(ybase >> 4) * 4096 + s * 512 + lane * 8;
        GLDS16(src, &Bs[0][0] + s * 512);
    }

    for (int ht = 0; ht < 8; ++ht) {
        const int tilebase = ybase + ht * 64;
        const int cur = ht & 1;

        __syncthreads();   // drains stage of ht; fences buffer reuse (ht-2)

        if (ht < 7) {
            const size_t nchunk = (size_t)((tilebase + 64) >> 4) * 4096;
#pragma unroll
            for (int g2 = 0; g2 < 8; ++g2) {
                int s = wv * 8 + g2;
                const unsigned short* src = xb2 + nchunk + s * 512 + lane * 8;
                GLDS16(src, &Bs[cur ^ 1][0] + s * 512);
            }
        }

#pragma unroll
        for (int tc = 0; tc < 4; ++tc) {
            const float bc = sq[tilebase + tc * 16 + c] * s2;
            // fragment-sequential: lane's data for (tc,kk) at (tc*8+kk)*1024B + lane*16B
            const unsigned short* bb = &Bs[cur][0] + tc * 8 * 512 + lane * 8;

            short8 bva[4];
#pragma unroll
            for (int kk = 0; kk < 4; ++kk)
                bva[kk] = *(const short8*)(bb + kk * 512);

            f32x4 acc[4];
#pragma unroll
            for (int tr = 0; tr < 4; ++tr)
#pragma unroll
                for (int r = 0; r < 4; ++r) acc[tr][r] = 0.0f;

#pragma unroll
            for (int kk = 0; kk < 4; ++kk)
#pragma unroll
                for (int tr = 0; tr < 4; ++tr)
                    acc[tr] = __builtin_amdgcn_mfma_f32_16x16x32_bf16(
                        av[tr][kk], bva[kk], acc[tr], 0, 0, 0);

            short8 bvb[4];
#pragma unroll
            for (int kk = 0; kk < 4; ++kk)
                bvb[kk] = *(const short8*)(bb + (kk + 4) * 512);

#pragma unroll
            for (int kk = 0; kk < 4; ++kk)
#pragma unroll
                for (int tr = 0; tr < 4; ++tr)
                    acc[tr] = __builtin_amdgcn_mfma_f32_16x16x32_bf16(
                        av[tr][kk + 4], bvb[kk], acc[tr], 0, 0, 0);

            // screen: conservative upper bound on t2 over this lane's 16 elems
            float gmax = acc[0][0];
#pragma unroll
            for (int tr = 0; tr < 4; ++tr)
#pragma unroll
                for (int r = 0; r < 4; ++r) gmax = fmaxf(gmax, acc[tr][r]);
            const float bound = fmaf(gmax, c2, armax + bc);

            if (__any(bound >= -115.0f)) {
                // exact slow path (diagonal-touching tiles, ~1%)
#pragma unroll
                for (int tr = 0; tr < 4; ++tr)
#pragma unroll
                    for (int r = 0; r < 4; ++r) {
                        float g = acc[tr][r];
                        float t2 = fminf(fmaf(g, c2, ar[tr * 4 + r] + bc), 0.0f);
                        float e = __builtin_amdgcn_exp2f(t2);
                        Sr[tr * 4 + r] += e;
                        Mr[tr * 4 + r] = fmaf(e, t2, Mr[tr * 4 + r]);
                    }
            }
            // else: all values underflow fp32 -> contribute exactly 0
        }
    }

    // row-sum commit: reduce across the 16 col-lanes (lane bits 0..3)
#pragma unroll
    for (int m = 1; m <= 8; m <<= 1)
#pragma unroll
        for (int k = 0; k < 16; ++k) {
            Sr[k] += __shfl_xor(Sr[k], m, 64);
            Mr[k] += __shfl_xor(Mr[k], m, 64);
        }
    if (c == 0) {
        const float LN2 = 0.69314718f;   // Mr holds sum e*log2(k); rescale to ln
#pragma unroll
        for (int k = 0; k < 16; ++k) {
            int row = rowbase + wv * 64 + (k >> 2) * 16 + q8 * 4 + (k & 3);
            atomicAdd(&Sarr[row], Sr[k]);
            atomicAdd(&Larr[row], Mr[k] * LN2);
        }
    }
}

// Kernel 2 (merged ctrl+scale): per row H = log(S) - L/S,
// cs = sigmoid(-(H - target)/T); write scaled features + control signal.
__global__ __launch_bounds__(256) void k_finish(const float* __restrict__ x,
                                                const float* __restrict__ Sarr,
                                                const float* __restrict__ Larr,
                                                const float* __restrict__ target,
                                                const float* __restrict__ temp,
                                                float* __restrict__ out) {
    const int gid = blockIdx.x * 256 + threadIdx.x;  // float4 index
    const int row = gid >> 6;                        // 64 float4 per row
    float S = Sarr[row], L = Larr[row];
    float H = __logf(S) - L / S;
    float z = (H - target[0]) / temp[0];
    float cs = 1.0f / (1.0f + __expf(z));
    float4 v = ((const float4*)x)[gid];
    float4 o;
    o.x = v.x * cs; o.y = v.y * cs; o.z = v.z * cs; o.w = v.w * cs;
    ((float4*)out)[gid] = o;
    if ((gid & 63) == 0) out[(size_t)N * D + row] = cs;  // control_signal section
}

extern "C" void kernel_launch(void* const* d_in, const int* in_sizes, int n_in,
                              void* d_out, int out_size, void* d_ws, size_t ws_size,
                              hipStream_t stream) {
    const float* x = (const float*)d_in[0];       // features [4,2048,256]
    const float* target = (const float*)d_in[7];  // target_entropy [1]
    const float* temp = (const float*)d_in[8];    // temperature [1]
    float* out = (float*)d_out;

    float* wsf = (float*)d_ws;
    float* sq = wsf;
    float* Sarr = wsf + N;
    float* Larr = wsf + 2 * N;

    // fragment-major bf16 copy of X: in ws if it fits, else park it in d_out's
    // first 4 MB (k_finish only writes d_out after k_gram has consumed xb2)
    const size_t need = 3 * (size_t)N * sizeof(float) + (size_t)N * D * sizeof(unsigned short);
    unsigned short* xb2 = (ws_size >= need) ? (unsigned short*)(wsf + 3 * N)
                                            : (unsigned short*)d_out;

    k_cvt<<<N / 64, 256, 0, stream>>>(x, xb2, sq, Sarr, Larr);
    k_gram<<<dim3(32, 16), 256, 0, stream>>>(xb2, sq, temp, Sarr, Larr);
    k_finish<<<(N * (D / 4)) / 256, 256, 0, stream>>>(x, Sarr, Larr, target, temp, out);
}